// Round 17
// baseline (61.665 us; speedup 1.0000x reference)
//
#include <hip/hip_runtime.h>
#include <math.h>

// out[c,i] = W[i]^2 * sum_{e: iInd[e]=i} x[c, jInd[e]]   (B=1, C=32)
//
// Pipeline (R16 skeleton; ONE change: TILE 4096->2048 with SLOTS 32->16):
//  1. transpose x [C,N] -> xtb [N,C] bf16; block 0 zeroes gcursor.
//  2. bin_edges: LDS-staged binning into NB=ceil(N/128) buckets, SLOTS=16,
//     TILE=2048 (4 edges/thread, one int4 pair), direct idx->bucket map
//     flush. LDS=45.9KB -> 3 blocks/CU, grid 782.
//  3. sort_reduce5: NB*4 blocks, 32-node sub-range each. Pass1 (int4-
//     vectorized) filter -> LDS compact + histogram; pass2 LDS sort;
//     register segment-sum (uint2 gathers + shfl_xor); plain store.
//  4. overflow_apply: applies the (normally ~empty) overflow list.

#define TCH 32
#define BSHIFT 7
#define BNODES 128
#define MAXNB 512
#define SLOTS 16
#define BIN_THREADS 512
#define TILE 2048
#define SR_THREADS 512
#define SPLIT2 4
#define NSUB 32
#define CMP_CAP 1536
#define SJ_CAP 1536

__device__ __forceinline__ unsigned short f32_to_bf16(float f) {
    unsigned int u = __float_as_uint(f);
    unsigned int r = (u + 0x7FFFu + ((u >> 16) & 1u)) >> 16;
    return (unsigned short)r;
}

__global__ void transpose_CN_to_NC_bf16(const float* __restrict__ x,
                                        unsigned short* __restrict__ xtb,
                                        int* __restrict__ gcursor,
                                        int NB, int N) {
    __shared__ float tile[32][33];
    const int tx = threadIdx.x;
    const int ty = threadIdx.y;
    if (blockIdx.x == 0) {  // fused counter init
        const int flat = ty * 32 + tx;
        for (int k = flat; k < NB + 1; k += 1024) gcursor[k] = 0;
    }
    const int n0 = blockIdx.x * 32;
    const int n = n0 + tx;
    if (n < N) tile[ty][tx] = x[(size_t)ty * N + n];
    __syncthreads();
    const int nw = n0 + ty;
    if (nw < N) xtb[(size_t)nw * TCH + tx] = f32_to_bf16(tile[tx][ty]);
}

__device__ __forceinline__ void push_ovf(int* ovf_cnt, int2* ovf, int ovf_cap,
                                         int i, int j) {
    const int p = atomicAdd(ovf_cnt, 1);
    if (p < ovf_cap) ovf[p] = make_int2(i, j);
}

__global__ __launch_bounds__(BIN_THREADS) void bin_edges(
    const int* __restrict__ iInd, const int* __restrict__ jInd,
    int* __restrict__ bins, int* __restrict__ gcursor,
    int* __restrict__ ovf_cnt, int2* __restrict__ ovf, int ovf_cap,
    int E, int NB, int cap) {
    __shared__ int stage[MAXNB * SLOTS];          // 32 KB
    __shared__ int scnt[MAXNB];                   // 2 KB
    __shared__ int sums[BIN_THREADS];             // 2 KB
    __shared__ unsigned short excl[MAXNB];        // 1 KB
    __shared__ unsigned short gbase[MAXNB];       // 1 KB (cap < 64K)
    __shared__ unsigned short bidx[TILE];         // 4 KB  => 45.9 KB total
    const int tid = threadIdx.x;

    scnt[tid] = 0;  // BIN_THREADS == MAXNB
    __syncthreads();

    // each thread owns 4 consecutive edges = one int4 pair
    const int eb = blockIdx.x * TILE + tid * 4;
    if (eb + 3 < E) {
        const int4 iv = *(const int4*)(iInd + eb);
        const int4 jv = *(const int4*)(jInd + eb);
        const int is[4] = {iv.x, iv.y, iv.z, iv.w};
        const int js[4] = {jv.x, jv.y, jv.z, jv.w};
#pragma unroll
        for (int k = 0; k < 4; ++k) {
            const int i = is[k], j = js[k];
            const int b = i >> BSHIFT;
            const int slot = atomicAdd(&scnt[b], 1);
            if (slot < SLOTS)
                stage[b * SLOTS + slot] = ((i & (BNODES - 1)) << 16) | j;
            else
                push_ovf(ovf_cnt, ovf, ovf_cap, i, j);
        }
    } else {
        for (int k = 0; k < 4; ++k) {
            const int e = eb + k;
            if (e < E) {
                const int i = iInd[e], j = jInd[e];
                const int b = i >> BSHIFT;
                const int slot = atomicAdd(&scnt[b], 1);
                if (slot < SLOTS)
                    stage[b * SLOTS + slot] = ((i & (BNODES - 1)) << 16) | j;
                else
                    push_ovf(ovf_cnt, ovf, ovf_cap, i, j);
            }
        }
    }
    __syncthreads();

    // exclusive scan of bucket counts (1 bucket per thread)
    const int cb = min(scnt[tid], SLOTS);
    sums[tid] = cb;
    __syncthreads();
    for (int off = 1; off < BIN_THREADS; off <<= 1) {
        const int v = (tid >= off) ? sums[tid - off] : 0;
        __syncthreads();
        sums[tid] += v;
        __syncthreads();
    }
    const int run0 = sums[tid] - cb;
    const int total = sums[BIN_THREADS - 1];
    excl[tid] = (unsigned short)run0;
    if (cb > 0) {
        gbase[tid] = (unsigned short)atomicAdd(&gcursor[tid], cb);
        for (int t = 0; t < cb; ++t)
            bidx[run0 + t] = (unsigned short)tid;
    }
    __syncthreads();

    // coalesced flush via direct idx->bucket map (1 LDS read, no search)
    for (int idx = tid; idx < total; idx += BIN_THREADS) {
        const int b = bidx[idx];
        const int k = idx - (int)excl[b];
        const int rec = stage[b * SLOTS + k];
        const int gslot = (int)gbase[b] + k;
        if (gslot < cap) {
            bins[(size_t)b * cap + gslot] = rec;
        } else {
            push_ovf(ovf_cnt, ovf, ovf_cap,
                     (b << BSHIFT) | (rec >> 16), rec & 0xFFFF);
        }
    }
}

// NB*4 blocks; block (bucket, sub) owns nodes [sub*32, sub*32+32).
__global__ __launch_bounds__(SR_THREADS) void sort_reduce5(
    const int* __restrict__ bins, const int* __restrict__ gcursor,
    const unsigned short* __restrict__ xtb, const float* __restrict__ W,
    float* __restrict__ out, int* __restrict__ ovf_cnt,
    int2* __restrict__ ovf, int ovf_cap, int N, int cap) {
    const int bucket = blockIdx.x >> 2;
    const int sub = blockIdx.x & (SPLIT2 - 1);
    __shared__ unsigned int cmp[CMP_CAP];     // 6 KB: in-range records
    __shared__ unsigned short sj[SJ_CAP];     // 3 KB: sorted j
    __shared__ float acc[NSUB * 33];          // 4.2 KB
    __shared__ int hcnt[NSUB];
    __shared__ int off2[NSUB + 1];
    __shared__ int cur[NSUB];
    __shared__ int ccnt;

    int cnt = gcursor[bucket];
    if (cnt > cap) cnt = cap;
    const int* rec = bins + (size_t)bucket * cap;

    if (threadIdx.x < NSUB) { hcnt[threadIdx.x] = 0; cur[threadIdx.x] = 0; }
    if (threadIdx.x == 0) ccnt = 0;
    __syncthreads();

    // pass 1 (single full-list scan, int4-vectorized): filter -> compact+hist
    const int cnt4 = cnt >> 2;
    const int4* rec4 = (const int4*)rec;     // cap % 4 == 0 -> 16B aligned
    for (int r = threadIdx.x; r < cnt4; r += SR_THREADS) {
        const int4 v = rec4[r];
        const unsigned int prs[4] = {(unsigned int)v.x, (unsigned int)v.y,
                                     (unsigned int)v.z, (unsigned int)v.w};
#pragma unroll
        for (int k = 0; k < 4; ++k) {
            const unsigned int pr = prs[k];
            const int il = (int)(pr >> 16);
            if ((il >> 5) == sub) {
                const int p = atomicAdd(&ccnt, 1);
                if (p < CMP_CAP) {
                    cmp[p] = pr;
                    atomicAdd(&hcnt[il & (NSUB - 1)], 1);
                } else {
                    push_ovf(ovf_cnt, ovf, ovf_cap,
                             (bucket << BSHIFT) | il, (int)(pr & 0xFFFF));
                }
            }
        }
    }
    for (int r = (cnt4 << 2) + threadIdx.x; r < cnt; r += SR_THREADS) {
        const unsigned int pr = (unsigned int)rec[r];
        const int il = (int)(pr >> 16);
        if ((il >> 5) == sub) {
            const int p = atomicAdd(&ccnt, 1);
            if (p < CMP_CAP) {
                cmp[p] = pr;
                atomicAdd(&hcnt[il & (NSUB - 1)], 1);
            } else {
                push_ovf(ovf_cnt, ovf, ovf_cap,
                         (bucket << BSHIFT) | il, (int)(pr & 0xFFFF));
            }
        }
    }
    __syncthreads();

    if (threadIdx.x == 0) {
        int run = 0;
        for (int k = 0; k < NSUB; ++k) { off2[k] = run; run += hcnt[k]; }
        off2[NSUB] = run;
    }
    __syncthreads();

    // pass 2: sort from the LDS compact list (1/4 size)
    const int cc = min(ccnt, CMP_CAP);
    for (int r = threadIdx.x; r < cc; r += SR_THREADS) {
        const unsigned int pr = cmp[r];
        const int il = (int)(pr >> 16) & (NSUB - 1);
        const int pos = off2[il] + atomicAdd(&cur[il], 1);
        sj[pos] = (unsigned short)(pr & 0xFFFF);   // pos < cc <= SJ_CAP
    }
    __syncthreads();

    // register segment-sum: 16 groups x 32 lanes.
    // rslot = lane>>3 (4 records in flight), c4 = (lane&7)*4 channels.
    const int lane = threadIdx.x & 31;
    const int g = threadIdx.x >> 5;
    const int rslot = lane >> 3;
    const int c4 = (lane & 7) * 4;
    for (int ill = g; ill < NSUB; ill += SR_THREADS / 32) {
        const int beg = off2[ill];
        const int end = off2[ill + 1];
        float a0 = 0.f, a1 = 0.f, a2 = 0.f, a3 = 0.f;
        int rb = beg;
        for (; rb + 8 <= end; rb += 8) {
            const int j0 = sj[rb + rslot];
            const int j1 = sj[rb + 4 + rslot];
            const uint2 u0 = *(const uint2*)(xtb + (size_t)j0 * TCH + c4);
            const uint2 u1 = *(const uint2*)(xtb + (size_t)j1 * TCH + c4);
            a0 += __uint_as_float(u0.x << 16);
            a1 += __uint_as_float(u0.x & 0xFFFF0000u);
            a2 += __uint_as_float(u0.y << 16);
            a3 += __uint_as_float(u0.y & 0xFFFF0000u);
            a0 += __uint_as_float(u1.x << 16);
            a1 += __uint_as_float(u1.x & 0xFFFF0000u);
            a2 += __uint_as_float(u1.y << 16);
            a3 += __uint_as_float(u1.y & 0xFFFF0000u);
        }
        {
            const int rr = rb + rslot;
            if (rr < end) {
                const int j = sj[rr];
                const uint2 u = *(const uint2*)(xtb + (size_t)j * TCH + c4);
                a0 += __uint_as_float(u.x << 16);
                a1 += __uint_as_float(u.x & 0xFFFF0000u);
                a2 += __uint_as_float(u.y << 16);
                a3 += __uint_as_float(u.y & 0xFFFF0000u);
            }
            const int rr2 = rb + 4 + rslot;
            if (rr2 < end) {
                const int j = sj[rr2];
                const uint2 u = *(const uint2*)(xtb + (size_t)j * TCH + c4);
                a0 += __uint_as_float(u.x << 16);
                a1 += __uint_as_float(u.x & 0xFFFF0000u);
                a2 += __uint_as_float(u.y << 16);
                a3 += __uint_as_float(u.y & 0xFFFF0000u);
            }
        }
        a0 += __shfl_xor(a0, 8);  a1 += __shfl_xor(a1, 8);
        a2 += __shfl_xor(a2, 8);  a3 += __shfl_xor(a3, 8);
        a0 += __shfl_xor(a0, 16); a1 += __shfl_xor(a1, 16);
        a2 += __shfl_xor(a2, 16); a3 += __shfl_xor(a3, 16);
        if (rslot == 0) {
            float* ap = &acc[ill * 33 + c4];
            ap[0] = a0; ap[1] = a1; ap[2] = a2; ap[3] = a3;
        }
    }
    __syncthreads();

    // exclusive-owner plain coalesced store
    const int i0 = (bucket << BSHIFT) + sub * NSUB;
    for (int k = threadIdx.x; k < NSUB * TCH; k += SR_THREADS) {
        const int ill = k & (NSUB - 1);
        const int cc2 = k >> 5;
        const int i = i0 + ill;
        if (i < N) {
            const float w = W[i];
            out[(size_t)cc2 * N + i] = w * w * acc[ill * 33 + cc2];
        }
    }
}

// applies overflow entries (normally ~empty) with atomics, AFTER sort_reduce5.
__global__ void overflow_apply(const int2* __restrict__ ovf,
                               const int* __restrict__ ovf_cnt,
                               const float* __restrict__ W,
                               const float* __restrict__ x,
                               float* __restrict__ out, int N, int ovf_cap) {
    int cnt = *ovf_cnt;
    if (cnt > ovf_cap) cnt = ovf_cap;
    const long long total = (long long)cnt * TCH;
    const long long stride = (long long)gridDim.x * blockDim.x;
    for (long long t = (long long)blockIdx.x * blockDim.x + threadIdx.x;
         t < total; t += stride) {
        const int e = (int)(t >> 5);
        const int c = (int)(t & 31);
        const int2 p = ovf[e];
        const float w = W[p.x];
        atomicAdd(&out[(size_t)c * N + p.x], w * w * x[(size_t)c * N + p.y]);
    }
}

// ---- fallback (ws too small / N too big for record packing) ----
__global__ void edge_scatter_cn(const int* __restrict__ iInd,
                                const int* __restrict__ jInd,
                                const float* __restrict__ W,
                                const float* __restrict__ x,
                                float* __restrict__ out, int E, int N) {
    const long long t = (long long)blockIdx.x * blockDim.x + threadIdx.x;
    const int e = (int)(t >> 5);
    const int c = (int)(t & 31);
    if (e < E) {
        const int i = iInd[e];
        const int j = jInd[e];
        const float w = W[i];
        atomicAdd(&out[(size_t)c * N + i], w * w * x[(size_t)c * N + j]);
    }
}

extern "C" void kernel_launch(void* const* d_in, const int* in_sizes, int n_in,
                              void* d_out, int out_size, void* d_ws, size_t ws_size,
                              hipStream_t stream) {
    const float* x    = (const float*)d_in[0];   // [1, C, N]
    const float* W    = (const float*)d_in[1];   // [N]
    const int*   iInd = (const int*)d_in[2];     // [E]
    const int*   jInd = (const int*)d_in[3];     // [E]

    const int N = in_sizes[1];
    const int E = in_sizes[2];
    float* out = (float*)d_out;

    const int NB = (N + BNODES - 1) >> BSHIFT;
    const int mean = (NB > 0) ? (E / NB) : 0;
    int cap = mean + (int)(8.0 * sqrt((double)(mean > 0 ? mean : 1))) + 64;
    cap = (cap + 3) & ~3;   // multiple of 4: int4-aligned bucket segments

    // ws layout (256B-aligned): xtb | bins | gcursor(NB)+ovf_cnt(1) | ovf
    const size_t A = 256;
    const size_t xtb_bytes = (((size_t)N * TCH * 2) + A - 1) / A * A;
    const size_t bin_bytes = (((size_t)NB * cap * 4) + A - 1) / A * A;
    const size_t cur_bytes = (((size_t)(NB + 1) * 4) + A - 1) / A * A;
    const size_t base_need = xtb_bytes + bin_bytes + cur_bytes;

    int ovf_cap = 0;
    if (ws_size > base_need) {
        size_t avail = ws_size - base_need;
        size_t oc = avail / sizeof(int2);
        if (oc > (size_t)(1 << 21)) oc = (size_t)(1 << 21);
        ovf_cap = (int)oc;
    }

    if (ws_size >= base_need && ovf_cap >= 65536 && NB <= MAXNB &&
        N <= 65536 && cap < 60000) {
        char* wsb = (char*)d_ws;
        unsigned short* xtb = (unsigned short*)wsb;
        int*   bins    = (int*)(wsb + xtb_bytes);
        int*   gcursor = (int*)(wsb + xtb_bytes + bin_bytes);
        int*   ovf_cnt = gcursor + NB;
        int2*  ovf     = (int2*)(wsb + base_need);

        const int ntiles = (N + 31) / 32;
        dim3 tb(32, 32);
        transpose_CN_to_NC_bf16<<<ntiles, tb, 0, stream>>>(
            x, xtb, gcursor, NB, N);

        const int bin_blocks = (E + TILE - 1) / TILE;
        bin_edges<<<bin_blocks, BIN_THREADS, 0, stream>>>(
            iInd, jInd, bins, gcursor, ovf_cnt, ovf, ovf_cap, E, NB, cap);

        sort_reduce5<<<NB * SPLIT2, SR_THREADS, 0, stream>>>(
            bins, gcursor, xtb, W, out, ovf_cnt, ovf, ovf_cap, N, cap);

        overflow_apply<<<128, 256, 0, stream>>>(
            ovf, ovf_cnt, W, x, out, N, ovf_cap);
    } else {
        hipMemsetAsync(out, 0, (size_t)out_size * sizeof(float), stream);
        const int threads = 256;
        const long long total = (long long)E * TCH;
        const int blocks = (int)((total + threads - 1) / threads);
        edge_scatter_cn<<<blocks, threads, 0, stream>>>(iInd, jInd, W, x, out, E, N);
    }
}

// Round 18
// 51.445 us; speedup vs baseline: 1.1987x; 1.1987x over previous
//
#include <hip/hip_runtime.h>
#include <math.h>

// out[c,i] = W[i]^2 * sum_{e: iInd[e]=i} x[c, jInd[e]]   (B=1, C=32)
//
// Pipeline (R16 skeleton; ONE change: wave-shfl scan in bin_edges, 18->2
// barriers):
//  1. transpose x [C,N] -> xtb [N,C] bf16; block 0 zeroes gcursor.
//  2. bin_edges: LDS-staged binning into NB=ceil(N/128) buckets, SLOTS=32,
//     TILE=4096, int4 edge loads, wave-shfl scan, direct idx->bucket map
//     flush. LDS=79.9KB.
//  3. sort_reduce5: NB*4 blocks, 32-node sub-range each. Pass1 (int4-
//     vectorized) filter -> LDS compact + histogram; pass2 LDS sort;
//     register segment-sum (uint2 gathers + shfl_xor); plain store.
//  4. overflow_apply: applies the (normally tiny) overflow list.

#define TCH 32
#define BSHIFT 7
#define BNODES 128
#define MAXNB 512
#define SLOTS 32
#define BIN_THREADS 512
#define TILE 4096
#define SR_THREADS 512
#define SPLIT2 4
#define NSUB 32
#define CMP_CAP 1536
#define SJ_CAP 1536

__device__ __forceinline__ unsigned short f32_to_bf16(float f) {
    unsigned int u = __float_as_uint(f);
    unsigned int r = (u + 0x7FFFu + ((u >> 16) & 1u)) >> 16;
    return (unsigned short)r;
}

__global__ void transpose_CN_to_NC_bf16(const float* __restrict__ x,
                                        unsigned short* __restrict__ xtb,
                                        int* __restrict__ gcursor,
                                        int NB, int N) {
    __shared__ float tile[32][33];
    const int tx = threadIdx.x;
    const int ty = threadIdx.y;
    if (blockIdx.x == 0) {  // fused counter init
        const int flat = ty * 32 + tx;
        for (int k = flat; k < NB + 1; k += 1024) gcursor[k] = 0;
    }
    const int n0 = blockIdx.x * 32;
    const int n = n0 + tx;
    if (n < N) tile[ty][tx] = x[(size_t)ty * N + n];
    __syncthreads();
    const int nw = n0 + ty;
    if (nw < N) xtb[(size_t)nw * TCH + tx] = f32_to_bf16(tile[tx][ty]);
}

__device__ __forceinline__ void push_ovf(int* ovf_cnt, int2* ovf, int ovf_cap,
                                         int i, int j) {
    const int p = atomicAdd(ovf_cnt, 1);
    if (p < ovf_cap) ovf[p] = make_int2(i, j);
}

__global__ __launch_bounds__(BIN_THREADS) void bin_edges(
    const int* __restrict__ iInd, const int* __restrict__ jInd,
    int* __restrict__ bins, int* __restrict__ gcursor,
    int* __restrict__ ovf_cnt, int2* __restrict__ ovf, int ovf_cap,
    int E, int NB, int cap) {
    __shared__ int stage[MAXNB * SLOTS];          // 64 KB
    __shared__ int scnt[MAXNB];                   // 2 KB
    __shared__ int wsum[8];                       // wave sums
    __shared__ unsigned short excl[MAXNB];        // 1 KB
    __shared__ unsigned short gbase[MAXNB];       // 1 KB (cap < 64K)
    __shared__ unsigned short bidx[TILE];         // 8 KB
    const int tid = threadIdx.x;

    scnt[tid] = 0;  // BIN_THREADS == MAXNB
    __syncthreads();

    // int4-vectorized: each thread owns 8 consecutive edges
    const int base = blockIdx.x * TILE + tid * 8;
#pragma unroll
    for (int q = 0; q < 2; ++q) {
        const int eb = base + q * 4;
        if (eb + 3 < E) {
            const int4 iv = *(const int4*)(iInd + eb);
            const int4 jv = *(const int4*)(jInd + eb);
            const int is[4] = {iv.x, iv.y, iv.z, iv.w};
            const int js[4] = {jv.x, jv.y, jv.z, jv.w};
#pragma unroll
            for (int k = 0; k < 4; ++k) {
                const int i = is[k], j = js[k];
                const int b = i >> BSHIFT;
                const int slot = atomicAdd(&scnt[b], 1);
                if (slot < SLOTS)
                    stage[b * SLOTS + slot] = ((i & (BNODES - 1)) << 16) | j;
                else
                    push_ovf(ovf_cnt, ovf, ovf_cap, i, j);
            }
        } else {
            for (int k = 0; k < 4; ++k) {
                const int e = eb + k;
                if (e < E) {
                    const int i = iInd[e], j = jInd[e];
                    const int b = i >> BSHIFT;
                    const int slot = atomicAdd(&scnt[b], 1);
                    if (slot < SLOTS)
                        stage[b * SLOTS + slot] = ((i & (BNODES - 1)) << 16) | j;
                    else
                        push_ovf(ovf_cnt, ovf, ovf_cap, i, j);
                }
            }
        }
    }
    __syncthreads();

    // wave-shfl exclusive scan of bucket counts (2 barriers total)
    const int cb = min(scnt[tid], SLOTS);
    const int lane = tid & 63;
    const int wv = tid >> 6;
    int v = cb;
#pragma unroll
    for (int off = 1; off < 64; off <<= 1) {
        const int u = __shfl_up(v, off);
        if (lane >= off) v += u;
    }
    if (lane == 63) wsum[wv] = v;
    __syncthreads();
    if (tid < 8) {
        int s = wsum[tid];
#pragma unroll
        for (int off = 1; off < 8; off <<= 1) {
            const int u = __shfl_up(s, off, 8);
            if (tid >= off) s += u;
        }
        wsum[tid] = s;
    }
    __syncthreads();
    const int incl = v + (wv == 0 ? 0 : wsum[wv - 1]);
    const int run0 = incl - cb;
    const int total = wsum[7];
    excl[tid] = (unsigned short)run0;
    if (cb > 0) {
        gbase[tid] = (unsigned short)atomicAdd(&gcursor[tid], cb);
        for (int t = 0; t < cb; ++t)
            bidx[run0 + t] = (unsigned short)tid;
    }
    __syncthreads();

    // coalesced flush via direct idx->bucket map (1 LDS read, no search)
    for (int idx = tid; idx < total; idx += BIN_THREADS) {
        const int b = bidx[idx];
        const int k = idx - (int)excl[b];
        const int rec = stage[b * SLOTS + k];
        const int gslot = (int)gbase[b] + k;
        if (gslot < cap) {
            bins[(size_t)b * cap + gslot] = rec;
        } else {
            push_ovf(ovf_cnt, ovf, ovf_cap,
                     (b << BSHIFT) | (rec >> 16), rec & 0xFFFF);
        }
    }
}

// NB*4 blocks; block (bucket, sub) owns nodes [sub*32, sub*32+32).
__global__ __launch_bounds__(SR_THREADS) void sort_reduce5(
    const int* __restrict__ bins, const int* __restrict__ gcursor,
    const unsigned short* __restrict__ xtb, const float* __restrict__ W,
    float* __restrict__ out, int* __restrict__ ovf_cnt,
    int2* __restrict__ ovf, int ovf_cap, int N, int cap) {
    const int bucket = blockIdx.x >> 2;
    const int sub = blockIdx.x & (SPLIT2 - 1);
    __shared__ unsigned int cmp[CMP_CAP];     // 6 KB: in-range records
    __shared__ unsigned short sj[SJ_CAP];     // 3 KB: sorted j
    __shared__ float acc[NSUB * 33];          // 4.2 KB
    __shared__ int hcnt[NSUB];
    __shared__ int off2[NSUB + 1];
    __shared__ int cur[NSUB];
    __shared__ int ccnt;

    int cnt = gcursor[bucket];
    if (cnt > cap) cnt = cap;
    const int* rec = bins + (size_t)bucket * cap;

    if (threadIdx.x < NSUB) { hcnt[threadIdx.x] = 0; cur[threadIdx.x] = 0; }
    if (threadIdx.x == 0) ccnt = 0;
    __syncthreads();

    // pass 1 (single full-list scan, int4-vectorized): filter -> compact+hist
    const int cnt4 = cnt >> 2;
    const int4* rec4 = (const int4*)rec;     // cap % 4 == 0 -> 16B aligned
    for (int r = threadIdx.x; r < cnt4; r += SR_THREADS) {
        const int4 v = rec4[r];
        const unsigned int prs[4] = {(unsigned int)v.x, (unsigned int)v.y,
                                     (unsigned int)v.z, (unsigned int)v.w};
#pragma unroll
        for (int k = 0; k < 4; ++k) {
            const unsigned int pr = prs[k];
            const int il = (int)(pr >> 16);
            if ((il >> 5) == sub) {
                const int p = atomicAdd(&ccnt, 1);
                if (p < CMP_CAP) {
                    cmp[p] = pr;
                    atomicAdd(&hcnt[il & (NSUB - 1)], 1);
                } else {
                    push_ovf(ovf_cnt, ovf, ovf_cap,
                             (bucket << BSHIFT) | il, (int)(pr & 0xFFFF));
                }
            }
        }
    }
    for (int r = (cnt4 << 2) + threadIdx.x; r < cnt; r += SR_THREADS) {
        const unsigned int pr = (unsigned int)rec[r];
        const int il = (int)(pr >> 16);
        if ((il >> 5) == sub) {
            const int p = atomicAdd(&ccnt, 1);
            if (p < CMP_CAP) {
                cmp[p] = pr;
                atomicAdd(&hcnt[il & (NSUB - 1)], 1);
            } else {
                push_ovf(ovf_cnt, ovf, ovf_cap,
                         (bucket << BSHIFT) | il, (int)(pr & 0xFFFF));
            }
        }
    }
    __syncthreads();

    if (threadIdx.x == 0) {
        int run = 0;
        for (int k = 0; k < NSUB; ++k) { off2[k] = run; run += hcnt[k]; }
        off2[NSUB] = run;
    }
    __syncthreads();

    // pass 2: sort from the LDS compact list (1/4 size)
    const int cc = min(ccnt, CMP_CAP);
    for (int r = threadIdx.x; r < cc; r += SR_THREADS) {
        const unsigned int pr = cmp[r];
        const int il = (int)(pr >> 16) & (NSUB - 1);
        const int pos = off2[il] + atomicAdd(&cur[il], 1);
        sj[pos] = (unsigned short)(pr & 0xFFFF);   // pos < cc <= SJ_CAP
    }
    __syncthreads();

    // register segment-sum: 16 groups x 32 lanes.
    // rslot = lane>>3 (4 records in flight), c4 = (lane&7)*4 channels.
    const int lane = threadIdx.x & 31;
    const int g = threadIdx.x >> 5;
    const int rslot = lane >> 3;
    const int c4 = (lane & 7) * 4;
    for (int ill = g; ill < NSUB; ill += SR_THREADS / 32) {
        const int beg = off2[ill];
        const int end = off2[ill + 1];
        float a0 = 0.f, a1 = 0.f, a2 = 0.f, a3 = 0.f;
        int rb = beg;
        for (; rb + 8 <= end; rb += 8) {
            const int j0 = sj[rb + rslot];
            const int j1 = sj[rb + 4 + rslot];
            const uint2 u0 = *(const uint2*)(xtb + (size_t)j0 * TCH + c4);
            const uint2 u1 = *(const uint2*)(xtb + (size_t)j1 * TCH + c4);
            a0 += __uint_as_float(u0.x << 16);
            a1 += __uint_as_float(u0.x & 0xFFFF0000u);
            a2 += __uint_as_float(u0.y << 16);
            a3 += __uint_as_float(u0.y & 0xFFFF0000u);
            a0 += __uint_as_float(u1.x << 16);
            a1 += __uint_as_float(u1.x & 0xFFFF0000u);
            a2 += __uint_as_float(u1.y << 16);
            a3 += __uint_as_float(u1.y & 0xFFFF0000u);
        }
        {
            const int rr = rb + rslot;
            if (rr < end) {
                const int j = sj[rr];
                const uint2 u = *(const uint2*)(xtb + (size_t)j * TCH + c4);
                a0 += __uint_as_float(u.x << 16);
                a1 += __uint_as_float(u.x & 0xFFFF0000u);
                a2 += __uint_as_float(u.y << 16);
                a3 += __uint_as_float(u.y & 0xFFFF0000u);
            }
            const int rr2 = rb + 4 + rslot;
            if (rr2 < end) {
                const int j = sj[rr2];
                const uint2 u = *(const uint2*)(xtb + (size_t)j * TCH + c4);
                a0 += __uint_as_float(u.x << 16);
                a1 += __uint_as_float(u.x & 0xFFFF0000u);
                a2 += __uint_as_float(u.y << 16);
                a3 += __uint_as_float(u.y & 0xFFFF0000u);
            }
        }
        a0 += __shfl_xor(a0, 8);  a1 += __shfl_xor(a1, 8);
        a2 += __shfl_xor(a2, 8);  a3 += __shfl_xor(a3, 8);
        a0 += __shfl_xor(a0, 16); a1 += __shfl_xor(a1, 16);
        a2 += __shfl_xor(a2, 16); a3 += __shfl_xor(a3, 16);
        if (rslot == 0) {
            float* ap = &acc[ill * 33 + c4];
            ap[0] = a0; ap[1] = a1; ap[2] = a2; ap[3] = a3;
        }
    }
    __syncthreads();

    // exclusive-owner plain coalesced store
    const int i0 = (bucket << BSHIFT) + sub * NSUB;
    for (int k = threadIdx.x; k < NSUB * TCH; k += SR_THREADS) {
        const int ill = k & (NSUB - 1);
        const int cc2 = k >> 5;
        const int i = i0 + ill;
        if (i < N) {
            const float w = W[i];
            out[(size_t)cc2 * N + i] = w * w * acc[ill * 33 + cc2];
        }
    }
}

// applies overflow entries (normally tiny) with atomics, AFTER sort_reduce5.
__global__ void overflow_apply(const int2* __restrict__ ovf,
                               const int* __restrict__ ovf_cnt,
                               const float* __restrict__ W,
                               const float* __restrict__ x,
                               float* __restrict__ out, int N, int ovf_cap) {
    int cnt = *ovf_cnt;
    if (cnt > ovf_cap) cnt = ovf_cap;
    const long long total = (long long)cnt * TCH;
    const long long stride = (long long)gridDim.x * blockDim.x;
    for (long long t = (long long)blockIdx.x * blockDim.x + threadIdx.x;
         t < total; t += stride) {
        const int e = (int)(t >> 5);
        const int c = (int)(t & 31);
        const int2 p = ovf[e];
        const float w = W[p.x];
        atomicAdd(&out[(size_t)c * N + p.x], w * w * x[(size_t)c * N + p.y]);
    }
}

// ---- fallback (ws too small / N too big for record packing) ----
__global__ void edge_scatter_cn(const int* __restrict__ iInd,
                                const int* __restrict__ jInd,
                                const float* __restrict__ W,
                                const float* __restrict__ x,
                                float* __restrict__ out, int E, int N) {
    const long long t = (long long)blockIdx.x * blockDim.x + threadIdx.x;
    const int e = (int)(t >> 5);
    const int c = (int)(t & 31);
    if (e < E) {
        const int i = iInd[e];
        const int j = jInd[e];
        const float w = W[i];
        atomicAdd(&out[(size_t)c * N + i], w * w * x[(size_t)c * N + j]);
    }
}

extern "C" void kernel_launch(void* const* d_in, const int* in_sizes, int n_in,
                              void* d_out, int out_size, void* d_ws, size_t ws_size,
                              hipStream_t stream) {
    const float* x    = (const float*)d_in[0];   // [1, C, N]
    const float* W    = (const float*)d_in[1];   // [N]
    const int*   iInd = (const int*)d_in[2];     // [E]
    const int*   jInd = (const int*)d_in[3];     // [E]

    const int N = in_sizes[1];
    const int E = in_sizes[2];
    float* out = (float*)d_out;

    const int NB = (N + BNODES - 1) >> BSHIFT;
    const int mean = (NB > 0) ? (E / NB) : 0;
    int cap = mean + (int)(8.0 * sqrt((double)(mean > 0 ? mean : 1))) + 64;
    cap = (cap + 3) & ~3;   // multiple of 4: int4-aligned bucket segments

    // ws layout (256B-aligned): xtb | bins | gcursor(NB)+ovf_cnt(1) | ovf
    const size_t A = 256;
    const size_t xtb_bytes = (((size_t)N * TCH * 2) + A - 1) / A * A;
    const size_t bin_bytes = (((size_t)NB * cap * 4) + A - 1) / A * A;
    const size_t cur_bytes = (((size_t)(NB + 1) * 4) + A - 1) / A * A;
    const size_t base_need = xtb_bytes + bin_bytes + cur_bytes;

    int ovf_cap = 0;
    if (ws_size > base_need) {
        size_t avail = ws_size - base_need;
        size_t oc = avail / sizeof(int2);
        if (oc > (size_t)(1 << 21)) oc = (size_t)(1 << 21);
        ovf_cap = (int)oc;
    }

    if (ws_size >= base_need && ovf_cap >= 65536 && NB <= MAXNB &&
        N <= 65536 && cap < 60000) {
        char* wsb = (char*)d_ws;
        unsigned short* xtb = (unsigned short*)wsb;
        int*   bins    = (int*)(wsb + xtb_bytes);
        int*   gcursor = (int*)(wsb + xtb_bytes + bin_bytes);
        int*   ovf_cnt = gcursor + NB;
        int2*  ovf     = (int2*)(wsb + base_need);

        const int ntiles = (N + 31) / 32;
        dim3 tb(32, 32);
        transpose_CN_to_NC_bf16<<<ntiles, tb, 0, stream>>>(
            x, xtb, gcursor, NB, N);

        const int bin_blocks = (E + TILE - 1) / TILE;
        bin_edges<<<bin_blocks, BIN_THREADS, 0, stream>>>(
            iInd, jInd, bins, gcursor, ovf_cnt, ovf, ovf_cap, E, NB, cap);

        sort_reduce5<<<NB * SPLIT2, SR_THREADS, 0, stream>>>(
            bins, gcursor, xtb, W, out, ovf_cnt, ovf, ovf_cap, N, cap);

        overflow_apply<<<128, 256, 0, stream>>>(
            ovf, ovf_cnt, W, x, out, N, ovf_cap);
    } else {
        hipMemsetAsync(out, 0, (size_t)out_size * sizeof(float), stream);
        const int threads = 256;
        const long long total = (long long)E * TCH;
        const int blocks = (int)((total + threads - 1) / threads);
        edge_scatter_cn<<<blocks, threads, 0, stream>>>(iInd, jInd, W, x, out, E, N);
    }
}

// Round 19
// 49.306 us; speedup vs baseline: 1.2506x; 1.0434x over previous
//
#include <hip/hip_runtime.h>
#include <math.h>

// out[c,i] = W[i]^2 * sum_{e: iInd[e]=i} x[c, jInd[e]]   (B=1, C=32)
//
// Pipeline (3 launches):
//  1. init_counters: zero gcursor+ovf_cnt (tiny).
//  2. bin_and_transpose: blocks [0,binB) = LDS-staged binning (SLOTS=32,
//     TILE=4096, int4 loads, wave-shfl scan, direct idx->bucket map flush);
//     blocks [binB, binB+ntiles) = x [C,N] -> xtb [N,C] bf16 transpose
//     (512 thr, LDS overlaid on stage). Transpose hides under binning.
//  3. sort_reduce7: NB*4 blocks, 32-node sub-range each. CMP/SJ >= cap so
//     overflow is impossible by construction; pass1 int4 filter -> compact
//     + hist; pass2 LDS sort; register segment-sum (uint2 + shfl_xor);
//     plain store; tail applies bin-stage overflow list (normally empty).

#define TCH 32
#define BSHIFT 7
#define BNODES 128
#define MAXNB 512
#define SLOTS 32
#define BIN_THREADS 512
#define TILE 4096
#define SR_THREADS 512
#define SPLIT2 4
#define NSUB 32
#define CMP_CAP 4736
#define SJ_CAP 4736

__device__ __forceinline__ unsigned short f32_to_bf16(float f) {
    unsigned int u = __float_as_uint(f);
    unsigned int r = (u + 0x7FFFu + ((u >> 16) & 1u)) >> 16;
    return (unsigned short)r;
}

__global__ void init_counters(int* __restrict__ gcursor, int NB) {
    for (int k = threadIdx.x; k < NB + 1; k += blockDim.x) gcursor[k] = 0;
}

__device__ __forceinline__ void push_ovf(int* ovf_cnt, int2* ovf, int ovf_cap,
                                         int i, int j) {
    const int p = atomicAdd(ovf_cnt, 1);
    if (p < ovf_cap) ovf[p] = make_int2(i, j);
}

__global__ __launch_bounds__(BIN_THREADS) void bin_and_transpose(
    const float* __restrict__ x, unsigned short* __restrict__ xtb,
    const int* __restrict__ iInd, const int* __restrict__ jInd,
    int* __restrict__ bins, int* __restrict__ gcursor,
    int* __restrict__ ovf_cnt, int2* __restrict__ ovf, int ovf_cap,
    int E, int NB, int cap, int N, int binB) {
    __shared__ int stage[MAXNB * SLOTS];          // 64 KB (overlaid by transpose)
    __shared__ int scnt[MAXNB];                   // 2 KB
    __shared__ int wsum[8];
    __shared__ unsigned short excl[MAXNB];        // 1 KB
    __shared__ unsigned short gbase[MAXNB];       // 1 KB (cap < 64K)
    __shared__ unsigned short bidx[TILE];         // 8 KB
    const int tid = threadIdx.x;

    if (blockIdx.x >= binB) {
        // ---- transpose part: 32x32 tile, 512 threads (2 rows/thread) ----
        float* tilef = (float*)stage;             // [32][33] floats = 4.2 KB
        const int t = blockIdx.x - binB;
        const int n0 = t * 32;
        const int tx = tid & 31;
        const int ty2 = tid >> 5;                 // 0..15
#pragma unroll
        for (int h = 0; h < 32; h += 16) {
            const int c = ty2 + h;
            const int n = n0 + tx;
            if (n < N) tilef[c * 33 + tx] = x[(size_t)c * N + n];
        }
        __syncthreads();
#pragma unroll
        for (int h = 0; h < 32; h += 16) {
            const int ny = ty2 + h;
            const int nw = n0 + ny;
            if (nw < N) xtb[(size_t)nw * TCH + tx] = f32_to_bf16(tilef[tx * 33 + ny]);
        }
        return;
    }

    // ---- binning part ----
    scnt[tid] = 0;  // BIN_THREADS == MAXNB
    __syncthreads();

    const int base = blockIdx.x * TILE + tid * 8;
#pragma unroll
    for (int q = 0; q < 2; ++q) {
        const int eb = base + q * 4;
        if (eb + 3 < E) {
            const int4 iv = *(const int4*)(iInd + eb);
            const int4 jv = *(const int4*)(jInd + eb);
            const int is[4] = {iv.x, iv.y, iv.z, iv.w};
            const int js[4] = {jv.x, jv.y, jv.z, jv.w};
#pragma unroll
            for (int k = 0; k < 4; ++k) {
                const int i = is[k], j = js[k];
                const int b = i >> BSHIFT;
                const int slot = atomicAdd(&scnt[b], 1);
                if (slot < SLOTS)
                    stage[b * SLOTS + slot] = ((i & (BNODES - 1)) << 16) | j;
                else
                    push_ovf(ovf_cnt, ovf, ovf_cap, i, j);
            }
        } else {
            for (int k = 0; k < 4; ++k) {
                const int e = eb + k;
                if (e < E) {
                    const int i = iInd[e], j = jInd[e];
                    const int b = i >> BSHIFT;
                    const int slot = atomicAdd(&scnt[b], 1);
                    if (slot < SLOTS)
                        stage[b * SLOTS + slot] = ((i & (BNODES - 1)) << 16) | j;
                    else
                        push_ovf(ovf_cnt, ovf, ovf_cap, i, j);
                }
            }
        }
    }
    __syncthreads();

    // wave-shfl exclusive scan of bucket counts (2 barriers)
    const int cb = min(scnt[tid], SLOTS);
    const int lane = tid & 63;
    const int wv = tid >> 6;
    int v = cb;
#pragma unroll
    for (int off = 1; off < 64; off <<= 1) {
        const int u = __shfl_up(v, off);
        if (lane >= off) v += u;
    }
    if (lane == 63) wsum[wv] = v;
    __syncthreads();
    if (tid < 8) {
        int s = wsum[tid];
#pragma unroll
        for (int off = 1; off < 8; off <<= 1) {
            const int u = __shfl_up(s, off, 8);
            if (tid >= off) s += u;
        }
        wsum[tid] = s;
    }
    __syncthreads();
    const int incl = v + (wv == 0 ? 0 : wsum[wv - 1]);
    const int run0 = incl - cb;
    const int total = wsum[7];
    excl[tid] = (unsigned short)run0;
    if (cb > 0) {
        gbase[tid] = (unsigned short)atomicAdd(&gcursor[tid], cb);
        for (int t = 0; t < cb; ++t)
            bidx[run0 + t] = (unsigned short)tid;
    }
    __syncthreads();

    // coalesced flush via direct idx->bucket map
    for (int idx = tid; idx < total; idx += BIN_THREADS) {
        const int b = bidx[idx];
        const int k = idx - (int)excl[b];
        const int rec = stage[b * SLOTS + k];
        const int gslot = (int)gbase[b] + k;
        if (gslot < cap) {
            bins[(size_t)b * cap + gslot] = rec;
        } else {
            push_ovf(ovf_cnt, ovf, ovf_cap,
                     (b << BSHIFT) | (rec >> 16), rec & 0xFFFF);
        }
    }
}

// NB*4 blocks; block (bucket, sub) owns nodes [sub*32, sub*32+32).
// CMP_CAP >= cap -> no overflow possible here. Tail applies ovf list.
__global__ __launch_bounds__(SR_THREADS) void sort_reduce7(
    const int* __restrict__ bins, const int* __restrict__ gcursor,
    const unsigned short* __restrict__ xtb, const float* __restrict__ W,
    const float* __restrict__ x, float* __restrict__ out,
    const int* __restrict__ ovf_cnt, const int2* __restrict__ ovf,
    int ovf_cap, int N, int cap) {
    const int bucket = blockIdx.x >> 2;
    const int sub = blockIdx.x & (SPLIT2 - 1);
    __shared__ unsigned int cmp[CMP_CAP];     // 18.9 KB
    __shared__ unsigned short sj[SJ_CAP];     // 9.5 KB
    __shared__ float acc[NSUB * 33];          // 4.2 KB
    __shared__ int hcnt[NSUB];
    __shared__ int off2[NSUB + 1];
    __shared__ int cur[NSUB];
    __shared__ int ccnt;

    int cnt = gcursor[bucket];
    if (cnt > cap) cnt = cap;
    const int* rec = bins + (size_t)bucket * cap;

    if (threadIdx.x < NSUB) { hcnt[threadIdx.x] = 0; cur[threadIdx.x] = 0; }
    if (threadIdx.x == 0) ccnt = 0;
    __syncthreads();

    // pass 1 (int4-vectorized full-list scan): filter -> compact + histogram
    const int cnt4 = cnt >> 2;
    const int4* rec4 = (const int4*)rec;     // cap % 4 == 0 -> 16B aligned
    for (int r = threadIdx.x; r < cnt4; r += SR_THREADS) {
        const int4 v = rec4[r];
        const unsigned int prs[4] = {(unsigned int)v.x, (unsigned int)v.y,
                                     (unsigned int)v.z, (unsigned int)v.w};
#pragma unroll
        for (int k = 0; k < 4; ++k) {
            const unsigned int pr = prs[k];
            const int il = (int)(pr >> 16);
            if ((il >> 5) == sub) {
                const int p = atomicAdd(&ccnt, 1);   // p < cnt <= cap <= CMP_CAP
                cmp[p] = pr;
                atomicAdd(&hcnt[il & (NSUB - 1)], 1);
            }
        }
    }
    for (int r = (cnt4 << 2) + threadIdx.x; r < cnt; r += SR_THREADS) {
        const unsigned int pr = (unsigned int)rec[r];
        const int il = (int)(pr >> 16);
        if ((il >> 5) == sub) {
            const int p = atomicAdd(&ccnt, 1);
            cmp[p] = pr;
            atomicAdd(&hcnt[il & (NSUB - 1)], 1);
        }
    }
    __syncthreads();

    if (threadIdx.x == 0) {
        int run = 0;
        for (int k = 0; k < NSUB; ++k) { off2[k] = run; run += hcnt[k]; }
        off2[NSUB] = run;
    }
    __syncthreads();

    // pass 2: sort from the LDS compact list
    const int cc = ccnt;
    for (int r = threadIdx.x; r < cc; r += SR_THREADS) {
        const unsigned int pr = cmp[r];
        const int il = (int)(pr >> 16) & (NSUB - 1);
        const int pos = off2[il] + atomicAdd(&cur[il], 1);
        sj[pos] = (unsigned short)(pr & 0xFFFF);
    }
    __syncthreads();

    // register segment-sum: 16 groups x 32 lanes.
    const int lane = threadIdx.x & 31;
    const int g = threadIdx.x >> 5;
    const int rslot = lane >> 3;
    const int c4 = (lane & 7) * 4;
    for (int ill = g; ill < NSUB; ill += SR_THREADS / 32) {
        const int beg = off2[ill];
        const int end = off2[ill + 1];
        float a0 = 0.f, a1 = 0.f, a2 = 0.f, a3 = 0.f;
        int rb = beg;
        for (; rb + 8 <= end; rb += 8) {
            const int j0 = sj[rb + rslot];
            const int j1 = sj[rb + 4 + rslot];
            const uint2 u0 = *(const uint2*)(xtb + (size_t)j0 * TCH + c4);
            const uint2 u1 = *(const uint2*)(xtb + (size_t)j1 * TCH + c4);
            a0 += __uint_as_float(u0.x << 16);
            a1 += __uint_as_float(u0.x & 0xFFFF0000u);
            a2 += __uint_as_float(u0.y << 16);
            a3 += __uint_as_float(u0.y & 0xFFFF0000u);
            a0 += __uint_as_float(u1.x << 16);
            a1 += __uint_as_float(u1.x & 0xFFFF0000u);
            a2 += __uint_as_float(u1.y << 16);
            a3 += __uint_as_float(u1.y & 0xFFFF0000u);
        }
        {
            const int rr = rb + rslot;
            if (rr < end) {
                const int j = sj[rr];
                const uint2 u = *(const uint2*)(xtb + (size_t)j * TCH + c4);
                a0 += __uint_as_float(u.x << 16);
                a1 += __uint_as_float(u.x & 0xFFFF0000u);
                a2 += __uint_as_float(u.y << 16);
                a3 += __uint_as_float(u.y & 0xFFFF0000u);
            }
            const int rr2 = rb + 4 + rslot;
            if (rr2 < end) {
                const int j = sj[rr2];
                const uint2 u = *(const uint2*)(xtb + (size_t)j * TCH + c4);
                a0 += __uint_as_float(u.x << 16);
                a1 += __uint_as_float(u.x & 0xFFFF0000u);
                a2 += __uint_as_float(u.y << 16);
                a3 += __uint_as_float(u.y & 0xFFFF0000u);
            }
        }
        a0 += __shfl_xor(a0, 8);  a1 += __shfl_xor(a1, 8);
        a2 += __shfl_xor(a2, 8);  a3 += __shfl_xor(a3, 8);
        a0 += __shfl_xor(a0, 16); a1 += __shfl_xor(a1, 16);
        a2 += __shfl_xor(a2, 16); a3 += __shfl_xor(a3, 16);
        if (rslot == 0) {
            float* ap = &acc[ill * 33 + c4];
            ap[0] = a0; ap[1] = a1; ap[2] = a2; ap[3] = a3;
        }
    }
    __syncthreads();

    // exclusive-owner plain coalesced store
    const int i0 = (bucket << BSHIFT) + sub * NSUB;
    for (int k = threadIdx.x; k < NSUB * TCH; k += SR_THREADS) {
        const int ill = k & (NSUB - 1);
        const int cc2 = k >> 5;
        const int i = i0 + ill;
        if (i < N) {
            const float w = W[i];
            out[(size_t)cc2 * N + i] = w * w * acc[ill * 33 + cc2];
        }
    }
    __syncthreads();

    // tail: apply bin-stage overflow entries in this block's node range
    int ocnt = *ovf_cnt;
    if (ocnt > ovf_cap) ocnt = ovf_cap;
    for (int e = threadIdx.x; e < ocnt; e += SR_THREADS) {
        const int2 p = ovf[e];
        if (p.x >= i0 && p.x < i0 + NSUB) {
            const float w = W[p.x];
            const float w2 = w * w;
            for (int c = 0; c < TCH; ++c)
                atomicAdd(&out[(size_t)c * N + p.x],
                          w2 * x[(size_t)c * N + p.y]);
        }
    }
}

// ---- fallback (ws too small / N too big / cap too big) ----
__global__ void edge_scatter_cn(const int* __restrict__ iInd,
                                const int* __restrict__ jInd,
                                const float* __restrict__ W,
                                const float* __restrict__ x,
                                float* __restrict__ out, int E, int N) {
    const long long t = (long long)blockIdx.x * blockDim.x + threadIdx.x;
    const int e = (int)(t >> 5);
    const int c = (int)(t & 31);
    if (e < E) {
        const int i = iInd[e];
        const int j = jInd[e];
        const float w = W[i];
        atomicAdd(&out[(size_t)c * N + i], w * w * x[(size_t)c * N + j]);
    }
}

extern "C" void kernel_launch(void* const* d_in, const int* in_sizes, int n_in,
                              void* d_out, int out_size, void* d_ws, size_t ws_size,
                              hipStream_t stream) {
    const float* x    = (const float*)d_in[0];   // [1, C, N]
    const float* W    = (const float*)d_in[1];   // [N]
    const int*   iInd = (const int*)d_in[2];     // [E]
    const int*   jInd = (const int*)d_in[3];     // [E]

    const int N = in_sizes[1];
    const int E = in_sizes[2];
    float* out = (float*)d_out;

    const int NB = (N + BNODES - 1) >> BSHIFT;
    const int mean = (NB > 0) ? (E / NB) : 0;
    int cap = mean + (int)(8.0 * sqrt((double)(mean > 0 ? mean : 1))) + 64;
    cap = (cap + 3) & ~3;   // multiple of 4: int4-aligned bucket segments

    // ws layout (256B-aligned): xtb | bins | gcursor(NB)+ovf_cnt(1) | ovf
    const size_t A = 256;
    const size_t xtb_bytes = (((size_t)N * TCH * 2) + A - 1) / A * A;
    const size_t bin_bytes = (((size_t)NB * cap * 4) + A - 1) / A * A;
    const size_t cur_bytes = (((size_t)(NB + 1) * 4) + A - 1) / A * A;
    const size_t base_need = xtb_bytes + bin_bytes + cur_bytes;

    int ovf_cap = 0;
    if (ws_size > base_need) {
        size_t avail = ws_size - base_need;
        size_t oc = avail / sizeof(int2);
        if (oc > (size_t)(1 << 21)) oc = (size_t)(1 << 21);
        ovf_cap = (int)oc;
    }

    if (ws_size >= base_need && ovf_cap >= 65536 && NB <= MAXNB &&
        N <= 65536 && cap <= CMP_CAP) {
        char* wsb = (char*)d_ws;
        unsigned short* xtb = (unsigned short*)wsb;
        int*   bins    = (int*)(wsb + xtb_bytes);
        int*   gcursor = (int*)(wsb + xtb_bytes + bin_bytes);
        int*   ovf_cnt = gcursor + NB;
        int2*  ovf     = (int2*)(wsb + base_need);

        init_counters<<<1, 512, 0, stream>>>(gcursor, NB);

        const int binB = (E + TILE - 1) / TILE;
        const int ntiles = (N + 31) / 32;
        bin_and_transpose<<<binB + ntiles, BIN_THREADS, 0, stream>>>(
            x, xtb, iInd, jInd, bins, gcursor, ovf_cnt, ovf, ovf_cap,
            E, NB, cap, N, binB);

        sort_reduce7<<<NB * SPLIT2, SR_THREADS, 0, stream>>>(
            bins, gcursor, xtb, W, x, out, ovf_cnt, ovf, ovf_cap, N, cap);
    } else {
        hipMemsetAsync(out, 0, (size_t)out_size * sizeof(float), stream);
        const int threads = 256;
        const long long total = (long long)E * TCH;
        const int blocks = (int)((total + threads - 1) / threads);
        edge_scatter_cn<<<blocks, threads, 0, stream>>>(iInd, jInd, W, x, out, E, N);
    }
}